// Round 5
// baseline (409.452 us; speedup 1.0000x reference)
//
#include <hip/hip_runtime.h>

// QuantizedSpectralConv: B=16, CIN=COUT=64, H=W=256, modes 64x64.
// rows r = 96..159 (h-axis modes), cols c = 32..95 (rfft w-axis modes).
// fwd:  T1[h][c] = sum_w x[h][w] e^{-2pi i (C0+c)w/256}
//       X[r][c]  = sum_h T1[h][c] e^{-2pi i (R0+r)h/256}
// mix:  Y[b,o,r,c] = sum_i X[b,i,r,c] * W[i,o,r,c]   (dequant)
// inv:  Z[h][c] = sum_r Y[r][c] e^{+2pi i (R0+r)h/256}
//       out[h][w] = bias + (2/65536) sum_c Re(Z[h][c] e^{+2pi i (C0+c)w/256})

#define HW    256
#define NCIN  64
#define NCOUT 64
#define NB    16
#define R0    96
#define C0    32

typedef __bf16 bf16x8 __attribute__((ext_vector_type(8)));
typedef float  f32x4  __attribute__((ext_vector_type(4)));

__device__ __forceinline__ unsigned short f2bf(float f) {
    unsigned u = __float_as_uint(f);
    unsigned r = (u + 0x7FFFu + ((u >> 16) & 1u)) >> 16;   // RTN-even
    return (unsigned short)r;
}
__device__ __forceinline__ bf16x8 ld_frag_g(const unsigned short* p) {
    return __builtin_bit_cast(bf16x8, *(const uint4*)p);
}
__device__ __forceinline__ unsigned pk2(float a, float b) {
    return (unsigned)f2bf(a) | ((unsigned)f2bf(b) << 16);
}

// ---------------- inverse-stage tables ----------------
// A1tab[h][k]: k<64 cos(2pi(R0+k)h/256), k>=64 sin(...)          [256][128]
// B2T[w][k]:   k<64 cos(2pi(C0+k)w/256), k>=64 -sin(...)         [256][128]
__global__ void build_tables2(unsigned short* __restrict__ A1tab,
                              unsigned short* __restrict__ B2T) {
    int idx = blockIdx.x * 256 + threadIdx.x;   // 0..32767
    int h = idx >> 7;
    int k = idx & 127;
    int kk = k & 63;
    const float TPO = 0.0245436926061702596754f;
    float s, c;
    int m1 = (((R0 + kk) * h) & 255);
    sincosf((float)m1 * TPO, &s, &c);
    A1tab[idx] = f2bf(k < 64 ? c : s);
    int m2 = (((C0 + kk) * h) & 255);
    sincosf((float)m2 * TPO, &s, &c);
    B2T[idx] = f2bf(k < 64 ? c : -s);
}

// ---------------- forward-stage tables ----------------
// B1fT[c][w] [128][256]: c<64 cos(2pi(C0+c)w/256), c>=64 -sin(2pi(C0+c-64)w/256)
// A2f[m][k]  [128][512]: r=m&63, h=k&255, th=2pi(R0+r)h/256
//   m<64 (Xr): k<256 cos, k>=256 sin ;  m>=64 (Xi): k<256 -sin, k>=256 cos
__global__ void build_fwd_tables(unsigned short* __restrict__ B1fT,
                                 unsigned short* __restrict__ A2f) {
    int idx = blockIdx.x * 256 + threadIdx.x;   // 0..98303
    const float TPO = 0.0245436926061702596754f;
    float s, c;
    if (idx < 32768) {
        int cc = idx >> 8, w = idx & 255;
        int m = (((C0 + (cc & 63)) * w) & 255);
        sincosf((float)m * TPO, &s, &c);
        B1fT[idx] = f2bf(cc < 64 ? c : -s);
    } else {
        int j = idx - 32768;
        int mr = j >> 9, k = j & 511;
        int m = (((R0 + (mr & 63)) * (k & 255)) & 255);
        sincosf((float)m * TPO, &s, &c);
        float v = (mr < 64) ? ((k < 256) ? c : s)
                            : ((k < 256) ? -s : c);
        A2f[j] = f2bf(v);
    }
}

// ---------------- forward: 16-wave block per (b,i) image ----------------
// GEMM-A: T1cat[256h][128cl] = x * B1f.  Wave w owns rows w*16..+15, ALL 128
//         cols: acc is only 8 frags (32 VGPR) so the 16 independent x-loads
//         per wave can be hoisted deep. B-frags straight from L2 table.
// GEMM-B: Xcat[128][64] = A2f[128][512] * Bop[512][64]; Bop = T1 transposed
//         in LDS (bf16, XOR-swizzled). 32 frags, 2 per wave.
__global__ __launch_bounds__(1024) void fwd_mfma(
        const float*          __restrict__ x,
        const unsigned short* __restrict__ B1fT,
        const unsigned short* __restrict__ A2f,
        float*                __restrict__ Xout) {
    __shared__ __align__(16) unsigned short smem[32768];   // 64 KB: Bop only
    int bi = blockIdx.x;
    const float* xim = x + (size_t)bi * 65536;
    int t = threadIdx.x, lane = t & 63, wv = t >> 6;       // wv 0..15
    int g = lane >> 4, lr = lane & 15;

    // ---- GEMM-A ----
    f32x4 acc[8];
    #pragma unroll
    for (int nf = 0; nf < 8; ++nf) acc[nf] = (f32x4)0.0f;

    const int h = wv * 16 + lr;
    const float* xrow = xim + h * 256;

    #pragma unroll
    for (int ks = 0; ks < 8; ++ks) {
        int k0 = ks * 32 + g * 8;
        float4 v0 = *(const float4*)(xrow + k0);
        float4 v1 = *(const float4*)(xrow + k0 + 4);
        bf16x8 b[8];
        #pragma unroll
        for (int nf = 0; nf < 8; ++nf)
            b[nf] = ld_frag_g(B1fT + (nf * 16 + lr) * 256 + k0);
        uint4 pk;
        pk.x = pk2(v0.x, v0.y); pk.y = pk2(v0.z, v0.w);
        pk.z = pk2(v1.x, v1.y); pk.w = pk2(v1.z, v1.w);
        bf16x8 a = __builtin_bit_cast(bf16x8, pk);
        #pragma unroll
        for (int nf = 0; nf < 8; ++nf)
            acc[nf] = __builtin_amdgcn_mfma_f32_16x16x32_bf16(a, b[nf], acc[nf], 0, 0, 0);
    }

    // ---- T1 -> Bop (bf16, swizzled) ----
    // frag element: row h' = wv*16 + g*4 + rg, col cl = nf*16 + lr
    {
        int h0 = wv * 16 + g * 4;
        #pragma unroll
        for (int nf = 0; nf < 8; ++nf) {
            int cl  = nf * 16 + lr;
            int col = cl & 63;
            int kk0 = (cl < 64) ? h0 : (256 + h0);
            uint2 pk;
            pk.x = pk2(acc[nf][0], acc[nf][1]);
            pk.y = pk2(acc[nf][2], acc[nf][3]);
            *(uint2*)&smem[col * 512 + (kk0 ^ ((col & 7) << 3))] = pk;
        }
    }
    __syncthreads();

    // ---- GEMM-B: wave w -> m-frag (w>>1), c-frags (w&1)*2 .. +1 ----
    int mw   = wv >> 1;
    int half = wv & 1;
    f32x4 acc2[2];
    acc2[0] = (f32x4)0.0f;
    acc2[1] = (f32x4)0.0f;
    const unsigned short* a2row = A2f + (mw * 16 + lr) * 512;
    #pragma unroll
    for (int ks = 0; ks < 16; ++ks) {
        int k0 = ks * 32 + g * 8;
        bf16x8 a2 = ld_frag_g(a2row + k0);
        #pragma unroll
        for (int j = 0; j < 2; ++j) {
            int c = half * 32 + j * 16 + lr;
            bf16x8 b2 = __builtin_bit_cast(bf16x8,
                          *(const uint4*)&smem[c * 512 + (k0 ^ ((c & 7) << 3))]);
            acc2[j] = __builtin_amdgcn_mfma_f32_16x16x32_bf16(a2, b2, acc2[j], 0, 0, 0);
        }
    }
    // X planes: [bi][p][r][c], p=0 real, p=1 imag (fp32)
    float* Xp = Xout + (size_t)bi * 8192;
    #pragma unroll
    for (int j = 0; j < 2; ++j)
        #pragma unroll
        for (int rg = 0; rg < 4; ++rg) {
            int m = mw * 16 + g * 4 + rg;
            int c = half * 32 + j * 16 + lr;
            Xp[(m >> 6) * 4096 + (m & 63) * 64 + c] = acc2[j][rg];
        }
}

// ---------------- stage C: channel mixing (unchanged) ----------------
__global__ __launch_bounds__(256) void mix_kernel(
        const float* __restrict__ X,
        const int*   __restrict__ q_real,
        const int*   __restrict__ q_imag,
        const float* __restrict__ s_r, const float* __restrict__ m_r,
        const float* __restrict__ s_i, const float* __restrict__ m_i,
        float2*      __restrict__ Y) {
    int rr = blockIdx.x;
    int ot = blockIdx.y;
    int t  = threadIdx.x;
    int c  = t & 63;
    int oq = t >> 6;
    int o  = ot * 4 + oq;
    float sr = *s_r, mr = *m_r, si = *s_i, mi = *m_i;
    __shared__ __align__(16) float2 xsh[16][64];
    float Yr[16], Yi[16];
    #pragma unroll
    for (int b = 0; b < 16; ++b) { Yr[b] = 0.f; Yi[b] = 0.f; }
    for (int i = 0; i < NCIN; ++i) {
        __syncthreads();
        #pragma unroll
        for (int l = t; l < 1024; l += 256) {
            int b = l >> 6, cc = l & 63;
            size_t base = (size_t)(b * NCIN + i) * 8192 + rr * 64 + cc;
            xsh[b][cc] = make_float2(X[base], X[base + 4096]);
        }
        __syncthreads();
        int widx = ((i * NCOUT + o) * 64 + rr) * 64 + c;
        float wr = (float)(q_real[widx] + 127) * sr + mr;
        float wi = (float)(q_imag[widx] + 127) * si + mi;
        #pragma unroll
        for (int b = 0; b < 16; ++b) {
            float2 xv = xsh[b][c];
            Yr[b] += xv.x * wr - xv.y * wi;
            Yi[b] += xv.x * wi + xv.y * wr;
        }
    }
    #pragma unroll
    for (int b = 0; b < 16; ++b)
        Y[(((size_t)b * NCOUT + o) * 64 + rr) * 64 + c] = make_float2(Yr[b], Yi[b]);
}

// ---------------- inverse: two bf16 MFMA GEMMs per (b,o) image (unchanged) ----------------
__global__ __launch_bounds__(256, 2) void inv_mfma(
        const float2*         __restrict__ Y,
        const unsigned short* __restrict__ A1tab,
        const unsigned short* __restrict__ B2T,
        const int*            __restrict__ q_bias,
        const float* __restrict__ b_s, const float* __restrict__ b_m,
        float*                __restrict__ out) {
    __shared__ __align__(16) unsigned short smem[32768];
    int bo   = blockIdx.x;
    int t    = threadIdx.x;
    int lane = t & 63;
    int wv   = t >> 6;
    int g    = lane >> 4;
    int lr   = lane & 15;
    float bias = ((float)q_bias[bo & 63] + 127.0f) * (*b_s) + (*b_m);

    const float2* Yp = Y + (size_t)bo * 4096;
    for (int l = t; l < 4096; l += 256) {
        int r = l >> 6, c = l & 63;
        float2 y = Yp[l];
        unsigned short yr  = f2bf(y.x);
        unsigned short yi  = f2bf(y.y);
        unsigned short nyi = f2bf(-y.y);
        int sw = (c & 7) << 3;
        smem[c * 128        + ((r)      ^ sw)] = yr;
        smem[c * 128        + ((64 + r) ^ sw)] = nyi;
        smem[(64 + c) * 128 + ((r)      ^ sw)] = yi;
        smem[(64 + c) * 128 + ((64 + r) ^ sw)] = yr;
    }
    __syncthreads();

    f32x4 acc[4][8];
    #pragma unroll
    for (int mf = 0; mf < 4; ++mf)
        #pragma unroll
        for (int nf = 0; nf < 8; ++nf) acc[mf][nf] = (f32x4)0.0f;

    #pragma unroll
    for (int ks = 0; ks < 4; ++ks) {
        int k0 = ks * 32 + g * 8;
        bf16x8 a[4], b[8];
        #pragma unroll
        for (int mf = 0; mf < 4; ++mf) {
            int h = wv * 64 + mf * 16 + lr;
            a[mf] = ld_frag_g(A1tab + h * 128 + k0);
        }
        #pragma unroll
        for (int nf = 0; nf < 8; ++nf) {
            int n = nf * 16 + lr;
            b[nf] = ld_frag_g(&smem[n * 128 + (k0 ^ ((n & 7) << 3))]);
        }
        #pragma unroll
        for (int mf = 0; mf < 4; ++mf)
            #pragma unroll
            for (int nf = 0; nf < 8; ++nf)
                acc[mf][nf] = __builtin_amdgcn_mfma_f32_16x16x32_bf16(
                                  a[mf], b[nf], acc[mf][nf], 0, 0, 0);
    }
    __syncthreads();

    #pragma unroll
    for (int mf = 0; mf < 4; ++mf)
        #pragma unroll
        for (int nf = 0; nf < 8; ++nf)
            #pragma unroll
            for (int rg = 0; rg < 4; ++rg) {
                int h = wv * 64 + mf * 16 + g * 4 + rg;
                int k = nf * 16 + lr;
                smem[h * 128 + (k ^ ((h & 7) << 3))] = f2bf(acc[mf][nf][rg]);
            }
    __syncthreads();

    const float scale = 2.0f / 65536.0f;
    float* outp = out + (size_t)bo * 65536;
    #pragma unroll
    for (int nh = 0; nh < 2; ++nh) {
        f32x4 acc2[4][8];
        #pragma unroll
        for (int mf = 0; mf < 4; ++mf)
            #pragma unroll
            for (int nf = 0; nf < 8; ++nf) acc2[mf][nf] = (f32x4)0.0f;

        #pragma unroll
        for (int ks = 0; ks < 4; ++ks) {
            int k0 = ks * 32 + g * 8;
            bf16x8 a[4], b[8];
            #pragma unroll
            for (int mf = 0; mf < 4; ++mf) {
                int h = wv * 64 + mf * 16 + lr;
                a[mf] = ld_frag_g(&smem[h * 128 + (k0 ^ ((h & 7) << 3))]);
            }
            #pragma unroll
            for (int nf = 0; nf < 8; ++nf) {
                int w = nh * 128 + nf * 16 + lr;
                b[nf] = ld_frag_g(B2T + w * 128 + k0);
            }
            #pragma unroll
            for (int mf = 0; mf < 4; ++mf)
                #pragma unroll
                for (int nf = 0; nf < 8; ++nf)
                    acc2[mf][nf] = __builtin_amdgcn_mfma_f32_16x16x32_bf16(
                                       a[mf], b[nf], acc2[mf][nf], 0, 0, 0);
        }
        #pragma unroll
        for (int mf = 0; mf < 4; ++mf)
            #pragma unroll
            for (int rg = 0; rg < 4; ++rg) {
                int h = wv * 64 + mf * 16 + g * 4 + rg;
                float* row = outp + h * 256 + nh * 128 + lr;
                #pragma unroll
                for (int nf = 0; nf < 8; ++nf)
                    row[nf * 16] = acc2[mf][nf][rg] * scale + bias;
            }
    }
}

extern "C" void kernel_launch(void* const* d_in, const int* in_sizes, int n_in,
                              void* d_out, int out_size, void* d_ws, size_t ws_size,
                              hipStream_t stream) {
    const float* x          = (const float*)d_in[0];
    const int*   q_real     = (const int*)  d_in[1];
    const int*   q_imag     = (const int*)  d_in[2];
    const int*   q_bias     = (const int*)  d_in[3];
    const float* scale_real = (const float*)d_in[4];
    const float* min_real   = (const float*)d_in[5];
    const float* scale_imag = (const float*)d_in[6];
    const float* min_imag   = (const float*)d_in[7];
    const float* b_scale    = (const float*)d_in[8];
    const float* b_min      = (const float*)d_in[9];
    float* out = (float*)d_out;

    float* ws = (float*)d_ws;
    // float-unit offsets:
    // A1tab bf16 [0,16384) ; B2T bf16 [16384,32768) ; B1fT bf16 [32768,49152)
    // A2f bf16 [49152,81920) ; X fp32 planes [81920, +8388608) ; Y float2 after.
    unsigned short* A1tab = (unsigned short*)(ws);
    unsigned short* B2T   = (unsigned short*)(ws + 16384);
    unsigned short* B1fT  = (unsigned short*)(ws + 32768);
    unsigned short* A2f   = (unsigned short*)(ws + 49152);
    float*          Xws   = (float*) (ws + 81920);
    float2*         Yws   = (float2*)(ws + 81920 + 8388608);

    build_tables2<<<128, 256, 0, stream>>>(A1tab, B2T);
    build_fwd_tables<<<384, 256, 0, stream>>>(B1fT, A2f);
    fwd_mfma<<<NB * NCIN, 1024, 0, stream>>>(x, B1fT, A2f, Xws);
    mix_kernel<<<dim3(64, 16), 256, 0, stream>>>(Xws, q_real, q_imag,
                                                 scale_real, min_real,
                                                 scale_imag, min_imag, Yws);
    inv_mfma<<<NB * NCOUT, 256, 0, stream>>>(Yws, A1tab, B2T,
                                             q_bias, b_scale, b_min, out);
}

// Round 6
// 332.012 us; speedup vs baseline: 1.2332x; 1.2332x over previous
//
#include <hip/hip_runtime.h>

// QuantizedSpectralConv: B=16, CIN=COUT=64, H=W=256, modes 64x64.
// rows r = 96..159 (h-axis modes), cols c = 32..95 (rfft w-axis modes).
// fwd:  T1[h][c] = sum_w x[h][w] e^{-2pi i (C0+c)w/256}
//       X[r][c]  = sum_h T1[h][c] e^{-2pi i (R0+r)h/256}
// mix:  Y[b,o,r,c] = sum_i X[b,i,r,c] * W[i,o,r,c]   (dequant)
// inv:  Z[h][c] = sum_r Y[r][c] e^{+2pi i (R0+r)h/256}
//       out[h][w] = bias + (2/65536) sum_c Re(Z[h][c] e^{+2pi i (C0+c)w/256})

#define HW    256
#define NCIN  64
#define NCOUT 64
#define NB    16
#define R0    96
#define C0    32

typedef __bf16 bf16x8 __attribute__((ext_vector_type(8)));
typedef float  f32x4  __attribute__((ext_vector_type(4)));

__device__ __forceinline__ unsigned short f2bf(float f) {
    unsigned u = __float_as_uint(f);
    unsigned r = (u + 0x7FFFu + ((u >> 16) & 1u)) >> 16;   // RTN-even
    return (unsigned short)r;
}
__device__ __forceinline__ bf16x8 ld_frag_g(const unsigned short* p) {
    return __builtin_bit_cast(bf16x8, *(const uint4*)p);
}
__device__ __forceinline__ unsigned pk2(float a, float b) {
    return (unsigned)f2bf(a) | ((unsigned)f2bf(b) << 16);
}
__device__ __forceinline__ void gload_lds16(const unsigned short* g, unsigned short* l) {
    __builtin_amdgcn_global_load_lds(
        (const __attribute__((address_space(1))) unsigned int*)g,
        (__attribute__((address_space(3))) unsigned int*)l, 16, 0, 0);
}

// ---------------- inverse-stage tables ----------------
// A1tab[h][k]: k<64 cos(2pi(R0+k)h/256), k>=64 sin(...)          [256][128]
// B2T[w][k]:   k<64 cos(2pi(C0+k)w/256), k>=64 -sin(...)         [256][128]
__global__ void build_tables2(unsigned short* __restrict__ A1tab,
                              unsigned short* __restrict__ B2T) {
    int idx = blockIdx.x * 256 + threadIdx.x;   // 0..32767
    int h = idx >> 7;
    int k = idx & 127;
    int kk = k & 63;
    const float TPO = 0.0245436926061702596754f;
    float s, c;
    int m1 = (((R0 + kk) * h) & 255);
    sincosf((float)m1 * TPO, &s, &c);
    A1tab[idx] = f2bf(k < 64 ? c : s);
    int m2 = (((C0 + kk) * h) & 255);
    sincosf((float)m2 * TPO, &s, &c);
    B2T[idx] = f2bf(k < 64 ? c : -s);
}

// ---------------- forward-stage tables ----------------
// B1fT: stored PRE-SWIZZLED in global: value(n,w) at n*256 + (w ^ ((n&7)<<3)).
//   n<64: cos(2pi(C0+n)w/256), n>=64: -sin(2pi(C0+n-64)w/256)    [128][256]
// A2f[m][k] [128][512]: r=m&63, h=k&255, th=2pi(R0+r)h/256
//   m<64 (Xr): k<256 cos, k>=256 sin ; m>=64 (Xi): k<256 -sin, k>=256 cos
__global__ void build_fwd_tables(unsigned short* __restrict__ B1fT,
                                 unsigned short* __restrict__ A2f) {
    int idx = blockIdx.x * 256 + threadIdx.x;   // 0..98303
    const float TPO = 0.0245436926061702596754f;
    float s, c;
    if (idx < 32768) {
        int cc = idx >> 8, w = idx & 255;
        int m = (((C0 + (cc & 63)) * w) & 255);
        sincosf((float)m * TPO, &s, &c);
        int sidx = (cc << 8) | (w ^ ((cc & 7) << 3));   // pre-swizzled slot
        B1fT[sidx] = f2bf(cc < 64 ? c : -s);
    } else {
        int j = idx - 32768;
        int mr = j >> 9, k = j & 511;
        int m = (((R0 + (mr & 63)) * (k & 255)) & 255);
        sincosf((float)m * TPO, &s, &c);
        float v = (mr < 64) ? ((k < 256) ? c : s)
                            : ((k < 256) ? -s : c);
        A2f[j] = f2bf(v);
    }
}

// ---------------- forward: 4-wave block per (b,i) image, m97-style ----------------
// Phase 0: B1fT (64 KB, pre-swizzled) -> LDS via global_load_lds (linear DMA).
// GEMM-A: T1cat[256h][128cl] = x * B1f. x-frags direct from global with an
//         explicit 1-deep register prefetch (xv[2][..]); B-frags from LDS
//         (conflict-free swizzled ds_read_b128). No per-iteration barriers.
// GEMM-B: Xcat[128][64] = A2f[128][512] * Bop[512][64]; Bop = T1 transposed
//         into the SAME LDS (union, barrier-separated).
__global__ __launch_bounds__(256, 2) void fwd_mfma(
        const float*          __restrict__ x,
        const unsigned short* __restrict__ B1fT,
        const unsigned short* __restrict__ A2f,
        float*                __restrict__ Xout) {
    __shared__ __align__(16) unsigned short smem[32768];   // 64 KB union
    int bi = blockIdx.x;
    const float* xim = x + (size_t)bi * 65536;
    int t = threadIdx.x, lane = t & 63, wv = t >> 6;       // wv 0..3
    int g = lane >> 4, lr = lane & 15;

    // ---- stage B1fT -> LDS (linear; table pre-swizzled in global) ----
    #pragma unroll
    for (int i = 0; i < 16; ++i)
        gload_lds16(B1fT + i * 2048 + t * 8, &smem[i * 2048 + wv * 512]);

    // ---- preload ks=0 x registers ----
    const float* xrow[4];
    #pragma unroll
    for (int mf = 0; mf < 4; ++mf)
        xrow[mf] = xim + (wv * 64 + mf * 16 + lr) * 256 + g * 8;
    float4 xv[2][4][2];
    #pragma unroll
    for (int mf = 0; mf < 4; ++mf) {
        xv[0][mf][0] = *(const float4*)(xrow[mf]);
        xv[0][mf][1] = *(const float4*)(xrow[mf] + 4);
    }
    __syncthreads();   // LDS staged (vmcnt(0) implied)

    // ---- GEMM-A ----
    f32x4 acc[4][8];
    #pragma unroll
    for (int mf = 0; mf < 4; ++mf)
        #pragma unroll
        for (int nf = 0; nf < 8; ++nf) acc[mf][nf] = (f32x4)0.0f;

    #pragma unroll
    for (int ks = 0; ks < 8; ++ks) {
        const int cur = ks & 1;
        if (ks < 7) {   // issue next-iteration x loads (1-deep prefetch)
            #pragma unroll
            for (int mf = 0; mf < 4; ++mf) {
                xv[cur ^ 1][mf][0] = *(const float4*)(xrow[mf] + (ks + 1) * 32);
                xv[cur ^ 1][mf][1] = *(const float4*)(xrow[mf] + (ks + 1) * 32 + 4);
            }
        }
        int k0 = ks * 32 + g * 8;
        bf16x8 b[8];
        #pragma unroll
        for (int nf = 0; nf < 8; ++nf) {
            int n = nf * 16 + lr;
            b[nf] = __builtin_bit_cast(bf16x8,
                      *(const uint4*)&smem[n * 256 + (k0 ^ ((n & 7) << 3))]);
        }
        bf16x8 a[4];
        #pragma unroll
        for (int mf = 0; mf < 4; ++mf) {
            uint4 pk;
            pk.x = pk2(xv[cur][mf][0].x, xv[cur][mf][0].y);
            pk.y = pk2(xv[cur][mf][0].z, xv[cur][mf][0].w);
            pk.z = pk2(xv[cur][mf][1].x, xv[cur][mf][1].y);
            pk.w = pk2(xv[cur][mf][1].z, xv[cur][mf][1].w);
            a[mf] = __builtin_bit_cast(bf16x8, pk);
        }
        #pragma unroll
        for (int mf = 0; mf < 4; ++mf)
            #pragma unroll
            for (int nf = 0; nf < 8; ++nf)
                acc[mf][nf] = __builtin_amdgcn_mfma_f32_16x16x32_bf16(
                                  a[mf], b[nf], acc[mf][nf], 0, 0, 0);
    }
    __syncthreads();   // all B1fT reads done; smem becomes Bop[64][512]

    // ---- T1 -> Bop (bf16, swizzled); C/D: row h=wv*64+mf*16+g*4+rg, col=nf*16+lr
    #pragma unroll
    for (int mf = 0; mf < 4; ++mf)
        #pragma unroll
        for (int nf = 0; nf < 8; ++nf) {
            int cl  = nf * 16 + lr;
            int col = cl & 63;
            int h0  = wv * 64 + mf * 16 + g * 4;
            int kk0 = (cl < 64) ? h0 : (256 + h0);
            uint2 pk;
            pk.x = pk2(acc[mf][nf][0], acc[mf][nf][1]);
            pk.y = pk2(acc[mf][nf][2], acc[mf][nf][3]);
            *(uint2*)&smem[col * 512 + (kk0 ^ ((col & 7) << 3))] = pk;
        }
    __syncthreads();

    // ---- GEMM-B: rows wv*32..+31 of Xcat ----
    f32x4 acc2[2][4];
    #pragma unroll
    for (int mf = 0; mf < 2; ++mf)
        #pragma unroll
        for (int nf = 0; nf < 4; ++nf) acc2[mf][nf] = (f32x4)0.0f;
    #pragma unroll
    for (int ks = 0; ks < 16; ++ks) {
        int k0 = ks * 32 + g * 8;
        bf16x8 a2[2], b2[4];
        #pragma unroll
        for (int mf = 0; mf < 2; ++mf) {
            int m = wv * 32 + mf * 16 + lr;
            a2[mf] = ld_frag_g(A2f + m * 512 + k0);
        }
        #pragma unroll
        for (int nf = 0; nf < 4; ++nf) {
            int c = nf * 16 + lr;
            b2[nf] = __builtin_bit_cast(bf16x8,
                       *(const uint4*)&smem[c * 512 + (k0 ^ ((c & 7) << 3))]);
        }
        #pragma unroll
        for (int mf = 0; mf < 2; ++mf)
            #pragma unroll
            for (int nf = 0; nf < 4; ++nf)
                acc2[mf][nf] = __builtin_amdgcn_mfma_f32_16x16x32_bf16(
                                   a2[mf], b2[nf], acc2[mf][nf], 0, 0, 0);
    }
    // X planes: [bi][p][r][c], p=0 real, p=1 imag (fp32)
    float* Xp = Xout + (size_t)bi * 8192;
    #pragma unroll
    for (int mf = 0; mf < 2; ++mf)
        #pragma unroll
        for (int nf = 0; nf < 4; ++nf)
            #pragma unroll
            for (int rg = 0; rg < 4; ++rg) {
                int m = wv * 32 + mf * 16 + g * 4 + rg;
                int c = nf * 16 + lr;
                Xp[(m >> 6) * 4096 + (m & 63) * 64 + c] = acc2[mf][nf][rg];
            }
}

// ---------------- stage C: channel mixing (unchanged) ----------------
__global__ __launch_bounds__(256) void mix_kernel(
        const float* __restrict__ X,
        const int*   __restrict__ q_real,
        const int*   __restrict__ q_imag,
        const float* __restrict__ s_r, const float* __restrict__ m_r,
        const float* __restrict__ s_i, const float* __restrict__ m_i,
        float2*      __restrict__ Y) {
    int rr = blockIdx.x;
    int ot = blockIdx.y;
    int t  = threadIdx.x;
    int c  = t & 63;
    int oq = t >> 6;
    int o  = ot * 4 + oq;
    float sr = *s_r, mr = *m_r, si = *s_i, mi = *m_i;
    __shared__ __align__(16) float2 xsh[16][64];
    float Yr[16], Yi[16];
    #pragma unroll
    for (int b = 0; b < 16; ++b) { Yr[b] = 0.f; Yi[b] = 0.f; }
    for (int i = 0; i < NCIN; ++i) {
        __syncthreads();
        #pragma unroll
        for (int l = t; l < 1024; l += 256) {
            int b = l >> 6, cc = l & 63;
            size_t base = (size_t)(b * NCIN + i) * 8192 + rr * 64 + cc;
            xsh[b][cc] = make_float2(X[base], X[base + 4096]);
        }
        __syncthreads();
        int widx = ((i * NCOUT + o) * 64 + rr) * 64 + c;
        float wr = (float)(q_real[widx] + 127) * sr + mr;
        float wi = (float)(q_imag[widx] + 127) * si + mi;
        #pragma unroll
        for (int b = 0; b < 16; ++b) {
            float2 xv = xsh[b][c];
            Yr[b] += xv.x * wr - xv.y * wi;
            Yi[b] += xv.x * wi + xv.y * wr;
        }
    }
    #pragma unroll
    for (int b = 0; b < 16; ++b)
        Y[(((size_t)b * NCOUT + o) * 64 + rr) * 64 + c] = make_float2(Yr[b], Yi[b]);
}

// ---------------- inverse: two bf16 MFMA GEMMs per (b,o) image (unchanged) ----------------
__global__ __launch_bounds__(256, 2) void inv_mfma(
        const float2*         __restrict__ Y,
        const unsigned short* __restrict__ A1tab,
        const unsigned short* __restrict__ B2T,
        const int*            __restrict__ q_bias,
        const float* __restrict__ b_s, const float* __restrict__ b_m,
        float*                __restrict__ out) {
    __shared__ __align__(16) unsigned short smem[32768];
    int bo   = blockIdx.x;
    int t    = threadIdx.x;
    int lane = t & 63;
    int wv   = t >> 6;
    int g    = lane >> 4;
    int lr   = lane & 15;
    float bias = ((float)q_bias[bo & 63] + 127.0f) * (*b_s) + (*b_m);

    const float2* Yp = Y + (size_t)bo * 4096;
    for (int l = t; l < 4096; l += 256) {
        int r = l >> 6, c = l & 63;
        float2 y = Yp[l];
        unsigned short yr  = f2bf(y.x);
        unsigned short yi  = f2bf(y.y);
        unsigned short nyi = f2bf(-y.y);
        int sw = (c & 7) << 3;
        smem[c * 128        + ((r)      ^ sw)] = yr;
        smem[c * 128        + ((64 + r) ^ sw)] = nyi;
        smem[(64 + c) * 128 + ((r)      ^ sw)] = yi;
        smem[(64 + c) * 128 + ((64 + r) ^ sw)] = yr;
    }
    __syncthreads();

    f32x4 acc[4][8];
    #pragma unroll
    for (int mf = 0; mf < 4; ++mf)
        #pragma unroll
        for (int nf = 0; nf < 8; ++nf) acc[mf][nf] = (f32x4)0.0f;

    #pragma unroll
    for (int ks = 0; ks < 4; ++ks) {
        int k0 = ks * 32 + g * 8;
        bf16x8 a[4], b[8];
        #pragma unroll
        for (int mf = 0; mf < 4; ++mf) {
            int h = wv * 64 + mf * 16 + lr;
            a[mf] = ld_frag_g(A1tab + h * 128 + k0);
        }
        #pragma unroll
        for (int nf = 0; nf < 8; ++nf) {
            int n = nf * 16 + lr;
            b[nf] = ld_frag_g(&smem[n * 128 + (k0 ^ ((n & 7) << 3))]);
        }
        #pragma unroll
        for (int mf = 0; mf < 4; ++mf)
            #pragma unroll
            for (int nf = 0; nf < 8; ++nf)
                acc[mf][nf] = __builtin_amdgcn_mfma_f32_16x16x32_bf16(
                                  a[mf], b[nf], acc[mf][nf], 0, 0, 0);
    }
    __syncthreads();

    #pragma unroll
    for (int mf = 0; mf < 4; ++mf)
        #pragma unroll
        for (int nf = 0; nf < 8; ++nf)
            #pragma unroll
            for (int rg = 0; rg < 4; ++rg) {
                int h = wv * 64 + mf * 16 + g * 4 + rg;
                int k = nf * 16 + lr;
                smem[h * 128 + (k ^ ((h & 7) << 3))] = f2bf(acc[mf][nf][rg]);
            }
    __syncthreads();

    const float scale = 2.0f / 65536.0f;
    float* outp = out + (size_t)bo * 65536;
    #pragma unroll
    for (int nh = 0; nh < 2; ++nh) {
        f32x4 acc2[4][8];
        #pragma unroll
        for (int mf = 0; mf < 4; ++mf)
            #pragma unroll
            for (int nf = 0; nf < 8; ++nf) acc2[mf][nf] = (f32x4)0.0f;

        #pragma unroll
        for (int ks = 0; ks < 4; ++ks) {
            int k0 = ks * 32 + g * 8;
            bf16x8 a[4], b[8];
            #pragma unroll
            for (int mf = 0; mf < 4; ++mf) {
                int h = wv * 64 + mf * 16 + lr;
                a[mf] = ld_frag_g(&smem[h * 128 + (k0 ^ ((h & 7) << 3))]);
            }
            #pragma unroll
            for (int nf = 0; nf < 8; ++nf) {
                int w = nh * 128 + nf * 16 + lr;
                b[nf] = ld_frag_g(B2T + w * 128 + k0);
            }
            #pragma unroll
            for (int mf = 0; mf < 4; ++mf)
                #pragma unroll
                for (int nf = 0; nf < 8; ++nf)
                    acc2[mf][nf] = __builtin_amdgcn_mfma_f32_16x16x32_bf16(
                                       a[mf], b[nf], acc2[mf][nf], 0, 0, 0);
        }
        #pragma unroll
        for (int mf = 0; mf < 4; ++mf)
            #pragma unroll
            for (int rg = 0; rg < 4; ++rg) {
                int h = wv * 64 + mf * 16 + g * 4 + rg;
                float* row = outp + h * 256 + nh * 128 + lr;
                #pragma unroll
                for (int nf = 0; nf < 8; ++nf)
                    row[nf * 16] = acc2[mf][nf][rg] * scale + bias;
            }
    }
}

extern "C" void kernel_launch(void* const* d_in, const int* in_sizes, int n_in,
                              void* d_out, int out_size, void* d_ws, size_t ws_size,
                              hipStream_t stream) {
    const float* x          = (const float*)d_in[0];
    const int*   q_real     = (const int*)  d_in[1];
    const int*   q_imag     = (const int*)  d_in[2];
    const int*   q_bias     = (const int*)  d_in[3];
    const float* scale_real = (const float*)d_in[4];
    const float* min_real   = (const float*)d_in[5];
    const float* scale_imag = (const float*)d_in[6];
    const float* min_imag   = (const float*)d_in[7];
    const float* b_scale    = (const float*)d_in[8];
    const float* b_min      = (const float*)d_in[9];
    float* out = (float*)d_out;

    float* ws = (float*)d_ws;
    // float-unit offsets:
    // A1tab bf16 [0,16384) ; B2T bf16 [16384,32768) ; B1fT bf16 [32768,49152)
    // A2f bf16 [49152,81920) ; X fp32 planes [81920, +8388608) ; Y float2 after.
    unsigned short* A1tab = (unsigned short*)(ws);
    unsigned short* B2T   = (unsigned short*)(ws + 16384);
    unsigned short* B1fT  = (unsigned short*)(ws + 32768);
    unsigned short* A2f   = (unsigned short*)(ws + 49152);
    float*          Xws   = (float*) (ws + 81920);
    float2*         Yws   = (float2*)(ws + 81920 + 8388608);

    build_tables2<<<128, 256, 0, stream>>>(A1tab, B2T);
    build_fwd_tables<<<384, 256, 0, stream>>>(B1fT, A2f);
    fwd_mfma<<<NB * NCIN, 256, 0, stream>>>(x, B1fT, A2f, Xws);
    mix_kernel<<<dim3(64, 16), 256, 0, stream>>>(Xws, q_real, q_imag,
                                                 scale_real, min_real,
                                                 scale_imag, min_imag, Yws);
    inv_mfma<<<NB * NCOUT, 256, 0, stream>>>(Yws, A1tab, B2T,
                                             q_bias, b_scale, b_min, out);
}

// Round 7
// 270.775 us; speedup vs baseline: 1.5121x; 1.2262x over previous
//
#include <hip/hip_runtime.h>

// QuantizedSpectralConv: B=16, CIN=COUT=64, H=W=256, modes 64x64.
// rows r = 96..159 (h-axis modes), cols c = 32..95 (rfft w-axis modes).
// fwd:  T1[h][c] = sum_w x[h][w] e^{-2pi i (C0+c)w/256}
//       X[r][c]  = sum_h T1[h][c] e^{-2pi i (R0+r)h/256}
// mix:  Y[b,o,r,c] = sum_i X[b,i,r,c] * W[i,o,r,c]   (dequant)
// inv:  Z[h][c] = sum_r Y[r][c] e^{+2pi i (R0+r)h/256}
//       out[h][w] = bias + (2/65536) sum_c Re(Z[h][c] e^{+2pi i (C0+c)w/256})

#define HW    256
#define NCIN  64
#define NCOUT 64
#define NB    16
#define R0    96
#define C0    32

typedef __bf16 bf16x8 __attribute__((ext_vector_type(8)));
typedef float  f32x4  __attribute__((ext_vector_type(4)));

__device__ __forceinline__ unsigned short f2bf(float f) {
    unsigned u = __float_as_uint(f);
    unsigned r = (u + 0x7FFFu + ((u >> 16) & 1u)) >> 16;   // RTN-even
    return (unsigned short)r;
}
__device__ __forceinline__ bf16x8 ld_frag_g(const unsigned short* p) {
    return __builtin_bit_cast(bf16x8, *(const uint4*)p);
}
__device__ __forceinline__ unsigned pk2(float a, float b) {
    return (unsigned)f2bf(a) | ((unsigned)f2bf(b) << 16);
}
__device__ __forceinline__ void gload_lds16(const unsigned short* g, unsigned short* l) {
    __builtin_amdgcn_global_load_lds(
        (const __attribute__((address_space(1))) unsigned int*)g,
        (__attribute__((address_space(3))) unsigned int*)l, 16, 0, 0);
}

// ---------------- inverse-stage tables ----------------
// A1tab[h][k]: k<64 cos(2pi(R0+k)h/256), k>=64 sin(...)          [256][128]
// B2T[w][k]:   k<64 cos(2pi(C0+k)w/256), k>=64 -sin(...)         [256][128]
__global__ void build_tables2(unsigned short* __restrict__ A1tab,
                              unsigned short* __restrict__ B2T) {
    int idx = blockIdx.x * 256 + threadIdx.x;   // 0..32767
    int h = idx >> 7;
    int k = idx & 127;
    int kk = k & 63;
    const float TPO = 0.0245436926061702596754f;
    float s, c;
    int m1 = (((R0 + kk) * h) & 255);
    sincosf((float)m1 * TPO, &s, &c);
    A1tab[idx] = f2bf(k < 64 ? c : s);
    int m2 = (((C0 + kk) * h) & 255);
    sincosf((float)m2 * TPO, &s, &c);
    B2T[idx] = f2bf(k < 64 ? c : -s);
}

// ---------------- forward-stage tables ----------------
// B1fT: stored PRE-SWIZZLED in global: value(n,w) at n*256 + (w ^ ((n&7)<<3)).
//   n<64: cos(2pi(C0+n)w/256), n>=64: -sin(2pi(C0+n-64)w/256)    [128][256]
// A2f[m][k] [128][512]: r=m&63, h=k&255, th=2pi(R0+r)h/256
//   m<64 (Xr): k<256 cos, k>=256 sin ; m>=64 (Xi): k<256 -sin, k>=256 cos
__global__ void build_fwd_tables(unsigned short* __restrict__ B1fT,
                                 unsigned short* __restrict__ A2f) {
    int idx = blockIdx.x * 256 + threadIdx.x;   // 0..98303
    const float TPO = 0.0245436926061702596754f;
    float s, c;
    if (idx < 32768) {
        int cc = idx >> 8, w = idx & 255;
        int m = (((C0 + (cc & 63)) * w) & 255);
        sincosf((float)m * TPO, &s, &c);
        int sidx = (cc << 8) | (w ^ ((cc & 7) << 3));   // pre-swizzled slot
        B1fT[sidx] = f2bf(cc < 64 ? c : -s);
    } else {
        int j = idx - 32768;
        int mr = j >> 9, k = j & 511;
        int m = (((R0 + (mr & 63)) * (k & 255)) & 255);
        sincosf((float)m * TPO, &s, &c);
        float v = (mr < 64) ? ((k < 256) ? c : s)
                            : ((k < 256) ? -s : c);
        A2f[j] = f2bf(v);
    }
}

// ---------------- forward: 4-wave block per (b,i) image (unchanged) ----------------
__global__ __launch_bounds__(256, 2) void fwd_mfma(
        const float*          __restrict__ x,
        const unsigned short* __restrict__ B1fT,
        const unsigned short* __restrict__ A2f,
        float*                __restrict__ Xout) {
    __shared__ __align__(16) unsigned short smem[32768];   // 64 KB union
    int bi = blockIdx.x;
    const float* xim = x + (size_t)bi * 65536;
    int t = threadIdx.x, lane = t & 63, wv = t >> 6;       // wv 0..3
    int g = lane >> 4, lr = lane & 15;

    #pragma unroll
    for (int i = 0; i < 16; ++i)
        gload_lds16(B1fT + i * 2048 + t * 8, &smem[i * 2048 + wv * 512]);

    const float* xrow[4];
    #pragma unroll
    for (int mf = 0; mf < 4; ++mf)
        xrow[mf] = xim + (wv * 64 + mf * 16 + lr) * 256 + g * 8;
    float4 xv[2][4][2];
    #pragma unroll
    for (int mf = 0; mf < 4; ++mf) {
        xv[0][mf][0] = *(const float4*)(xrow[mf]);
        xv[0][mf][1] = *(const float4*)(xrow[mf] + 4);
    }
    __syncthreads();

    f32x4 acc[4][8];
    #pragma unroll
    for (int mf = 0; mf < 4; ++mf)
        #pragma unroll
        for (int nf = 0; nf < 8; ++nf) acc[mf][nf] = (f32x4)0.0f;

    #pragma unroll
    for (int ks = 0; ks < 8; ++ks) {
        const int cur = ks & 1;
        if (ks < 7) {
            #pragma unroll
            for (int mf = 0; mf < 4; ++mf) {
                xv[cur ^ 1][mf][0] = *(const float4*)(xrow[mf] + (ks + 1) * 32);
                xv[cur ^ 1][mf][1] = *(const float4*)(xrow[mf] + (ks + 1) * 32 + 4);
            }
        }
        int k0 = ks * 32 + g * 8;
        bf16x8 b[8];
        #pragma unroll
        for (int nf = 0; nf < 8; ++nf) {
            int n = nf * 16 + lr;
            b[nf] = __builtin_bit_cast(bf16x8,
                      *(const uint4*)&smem[n * 256 + (k0 ^ ((n & 7) << 3))]);
        }
        bf16x8 a[4];
        #pragma unroll
        for (int mf = 0; mf < 4; ++mf) {
            uint4 pk;
            pk.x = pk2(xv[cur][mf][0].x, xv[cur][mf][0].y);
            pk.y = pk2(xv[cur][mf][0].z, xv[cur][mf][0].w);
            pk.z = pk2(xv[cur][mf][1].x, xv[cur][mf][1].y);
            pk.w = pk2(xv[cur][mf][1].z, xv[cur][mf][1].w);
            a[mf] = __builtin_bit_cast(bf16x8, pk);
        }
        #pragma unroll
        for (int mf = 0; mf < 4; ++mf)
            #pragma unroll
            for (int nf = 0; nf < 8; ++nf)
                acc[mf][nf] = __builtin_amdgcn_mfma_f32_16x16x32_bf16(
                                  a[mf], b[nf], acc[mf][nf], 0, 0, 0);
    }
    __syncthreads();

    #pragma unroll
    for (int mf = 0; mf < 4; ++mf)
        #pragma unroll
        for (int nf = 0; nf < 8; ++nf) {
            int cl  = nf * 16 + lr;
            int col = cl & 63;
            int h0  = wv * 64 + mf * 16 + g * 4;
            int kk0 = (cl < 64) ? h0 : (256 + h0);
            uint2 pk;
            pk.x = pk2(acc[mf][nf][0], acc[mf][nf][1]);
            pk.y = pk2(acc[mf][nf][2], acc[mf][nf][3]);
            *(uint2*)&smem[col * 512 + (kk0 ^ ((col & 7) << 3))] = pk;
        }
    __syncthreads();

    f32x4 acc2[2][4];
    #pragma unroll
    for (int mf = 0; mf < 2; ++mf)
        #pragma unroll
        for (int nf = 0; nf < 4; ++nf) acc2[mf][nf] = (f32x4)0.0f;
    #pragma unroll
    for (int ks = 0; ks < 16; ++ks) {
        int k0 = ks * 32 + g * 8;
        bf16x8 a2[2], b2[4];
        #pragma unroll
        for (int mf = 0; mf < 2; ++mf) {
            int m = wv * 32 + mf * 16 + lr;
            a2[mf] = ld_frag_g(A2f + m * 512 + k0);
        }
        #pragma unroll
        for (int nf = 0; nf < 4; ++nf) {
            int c = nf * 16 + lr;
            b2[nf] = __builtin_bit_cast(bf16x8,
                       *(const uint4*)&smem[c * 512 + (k0 ^ ((c & 7) << 3))]);
        }
        #pragma unroll
        for (int mf = 0; mf < 2; ++mf)
            #pragma unroll
            for (int nf = 0; nf < 4; ++nf)
                acc2[mf][nf] = __builtin_amdgcn_mfma_f32_16x16x32_bf16(
                                   a2[mf], b2[nf], acc2[mf][nf], 0, 0, 0);
    }
    float* Xp = Xout + (size_t)bi * 8192;
    #pragma unroll
    for (int mf = 0; mf < 2; ++mf)
        #pragma unroll
        for (int nf = 0; nf < 4; ++nf)
            #pragma unroll
            for (int rg = 0; rg < 4; ++rg) {
                int m = wv * 32 + mf * 16 + g * 4 + rg;
                int c = nf * 16 + lr;
                Xp[(m >> 6) * 4096 + (m & 63) * 64 + c] = acc2[mf][nf][rg];
            }
}

// ---------------- stage C: pipelined streaming channel mix ----------------
// grid (rr=64, ot=8); thread = (oq = t>>5 -> o = ot*8+oq, cp = t&31 -> c = 2cp,2cp+1)
// Weights int2-prefetched 2 iters ahead; X double-buffered in LDS, one barrier/iter.
__global__ __launch_bounds__(256) void mix_kernel(
        const float* __restrict__ X,
        const int*   __restrict__ q_real,
        const int*   __restrict__ q_imag,
        const float* __restrict__ s_r, const float* __restrict__ m_r,
        const float* __restrict__ s_i, const float* __restrict__ m_i,
        float2*      __restrict__ Y) {
    int rr = blockIdx.x;              // 0..63
    int ot = blockIdx.y;              // 0..7
    int t  = threadIdx.x;
    int cp = t & 31;                  // c-pair
    int oq = t >> 5;                  // 0..7
    int o  = ot * 8 + oq;
    int c0 = cp * 2;
    float sr = *s_r, mr = *m_r, si = *s_i, mi = *m_i;

    __shared__ float xr_sh[2][16][72];   // stride 72: write conflicts <=4-way
    __shared__ float xi_sh[2][16][72];

    // staging role: thread loads (b = t>>4, c-quad = t&15) as float4 per plane
    int sb  = t >> 4;
    int scq = t & 15;
    const float* xbase = X + (size_t)sb * 64 * 8192 + rr * 64 + scq * 4;

    // weight pointers: widx(i) = i*262144 + o*4096 + rr*64 + c
    const int* qrp = q_real + (size_t)o * 4096 + rr * 64 + c0;
    const int* qip = q_imag + (size_t)o * 4096 + rr * 64 + c0;

    float Yr0[16], Yi0[16], Yr1[16], Yi1[16];
    #pragma unroll
    for (int b = 0; b < 16; ++b) { Yr0[b] = 0.f; Yi0[b] = 0.f; Yr1[b] = 0.f; Yi1[b] = 0.f; }

    // preload weights for i=0,1 (slots 0,1)
    int2 wqr[2], wqi[2];
    wqr[0] = *(const int2*)(qrp);
    wqi[0] = *(const int2*)(qip);
    wqr[1] = *(const int2*)(qrp + 262144);
    wqi[1] = *(const int2*)(qip + 262144);
    // preload + stage X for i=0
    {
        float4 gr = *(const float4*)(xbase);
        float4 gi = *(const float4*)(xbase + 4096);
        *(float4*)&xr_sh[0][sb][scq * 4] = gr;
        *(float4*)&xi_sh[0][sb][scq * 4] = gi;
    }
    __syncthreads();

    #pragma unroll 2
    for (int i = 0; i < 64; ++i) {
        const int cur = i & 1;
        // issue X loads for i+1 (consumed by ds_write after compute)
        float4 gr, gi;
        if (i < 63) {
            gr = *(const float4*)(xbase + (size_t)(i + 1) * 8192);
            gi = *(const float4*)(xbase + (size_t)(i + 1) * 8192 + 4096);
        }
        // dequant weights for i (loaded 2 iters ago)
        float wr0 = (float)(wqr[cur].x + 127) * sr + mr;
        float wr1 = (float)(wqr[cur].y + 127) * sr + mr;
        float wi0 = (float)(wqi[cur].x + 127) * si + mi;
        float wi1 = (float)(wqi[cur].y + 127) * si + mi;
        // issue weight loads for i+2 into the freed slot
        if (i < 62) {
            wqr[cur] = *(const int2*)(qrp + (size_t)(i + 2) * 262144);
            wqi[cur] = *(const int2*)(qip + (size_t)(i + 2) * 262144);
        }
        // compute
        #pragma unroll
        for (int b = 0; b < 16; ++b) {
            float2 xr = *(const float2*)&xr_sh[cur][b][c0];
            float2 xi = *(const float2*)&xi_sh[cur][b][c0];
            Yr0[b] += xr.x * wr0 - xi.x * wi0;
            Yi0[b] += xr.x * wi0 + xi.x * wr0;
            Yr1[b] += xr.y * wr1 - xi.y * wi1;
            Yi1[b] += xr.y * wi1 + xi.y * wr1;
        }
        // write staged X to the other buffer; single barrier per iter
        if (i < 63) {
            *(float4*)&xr_sh[cur ^ 1][sb][scq * 4] = gr;
            *(float4*)&xi_sh[cur ^ 1][sb][scq * 4] = gi;
            __syncthreads();
        }
    }

    // epilogue: Y[b, o, rr, c0..c0+1] as float4
    #pragma unroll
    for (int b = 0; b < 16; ++b) {
        float4 v = make_float4(Yr0[b], Yi0[b], Yr1[b], Yi1[b]);
        *(float4*)&Y[(size_t)b * 262144 + (size_t)o * 4096 + rr * 64 + c0] = v;
    }
}

// ---------------- inverse: two bf16 MFMA GEMMs per (b,o) image (unchanged) ----------------
__global__ __launch_bounds__(256, 2) void inv_mfma(
        const float2*         __restrict__ Y,
        const unsigned short* __restrict__ A1tab,
        const unsigned short* __restrict__ B2T,
        const int*            __restrict__ q_bias,
        const float* __restrict__ b_s, const float* __restrict__ b_m,
        float*                __restrict__ out) {
    __shared__ __align__(16) unsigned short smem[32768];
    int bo   = blockIdx.x;
    int t    = threadIdx.x;
    int lane = t & 63;
    int wv   = t >> 6;
    int g    = lane >> 4;
    int lr   = lane & 15;
    float bias = ((float)q_bias[bo & 63] + 127.0f) * (*b_s) + (*b_m);

    const float2* Yp = Y + (size_t)bo * 4096;
    for (int l = t; l < 4096; l += 256) {
        int r = l >> 6, c = l & 63;
        float2 y = Yp[l];
        unsigned short yr  = f2bf(y.x);
        unsigned short yi  = f2bf(y.y);
        unsigned short nyi = f2bf(-y.y);
        int sw = (c & 7) << 3;
        smem[c * 128        + ((r)      ^ sw)] = yr;
        smem[c * 128        + ((64 + r) ^ sw)] = nyi;
        smem[(64 + c) * 128 + ((r)      ^ sw)] = yi;
        smem[(64 + c) * 128 + ((64 + r) ^ sw)] = yr;
    }
    __syncthreads();

    f32x4 acc[4][8];
    #pragma unroll
    for (int mf = 0; mf < 4; ++mf)
        #pragma unroll
        for (int nf = 0; nf < 8; ++nf) acc[mf][nf] = (f32x4)0.0f;

    #pragma unroll
    for (int ks = 0; ks < 4; ++ks) {
        int k0 = ks * 32 + g * 8;
        bf16x8 a[4], b[8];
        #pragma unroll
        for (int mf = 0; mf < 4; ++mf) {
            int h = wv * 64 + mf * 16 + lr;
            a[mf] = ld_frag_g(A1tab + h * 128 + k0);
        }
        #pragma unroll
        for (int nf = 0; nf < 8; ++nf) {
            int n = nf * 16 + lr;
            b[nf] = ld_frag_g(&smem[n * 128 + (k0 ^ ((n & 7) << 3))]);
        }
        #pragma unroll
        for (int mf = 0; mf < 4; ++mf)
            #pragma unroll
            for (int nf = 0; nf < 8; ++nf)
                acc[mf][nf] = __builtin_amdgcn_mfma_f32_16x16x32_bf16(
                                  a[mf], b[nf], acc[mf][nf], 0, 0, 0);
    }
    __syncthreads();

    #pragma unroll
    for (int mf = 0; mf < 4; ++mf)
        #pragma unroll
        for (int nf = 0; nf < 8; ++nf)
            #pragma unroll
            for (int rg = 0; rg < 4; ++rg) {
                int h = wv * 64 + mf * 16 + g * 4 + rg;
                int k = nf * 16 + lr;
                smem[h * 128 + (k ^ ((h & 7) << 3))] = f2bf(acc[mf][nf][rg]);
            }
    __syncthreads();

    const float scale = 2.0f / 65536.0f;
    float* outp = out + (size_t)bo * 65536;
    #pragma unroll
    for (int nh = 0; nh < 2; ++nh) {
        f32x4 acc2[4][8];
        #pragma unroll
        for (int mf = 0; mf < 4; ++mf)
            #pragma unroll
            for (int nf = 0; nf < 8; ++nf) acc2[mf][nf] = (f32x4)0.0f;

        #pragma unroll
        for (int ks = 0; ks < 4; ++ks) {
            int k0 = ks * 32 + g * 8;
            bf16x8 a[4], b[8];
            #pragma unroll
            for (int mf = 0; mf < 4; ++mf) {
                int h = wv * 64 + mf * 16 + lr;
                a[mf] = ld_frag_g(&smem[h * 128 + (k0 ^ ((h & 7) << 3))]);
            }
            #pragma unroll
            for (int nf = 0; nf < 8; ++nf) {
                int w = nh * 128 + nf * 16 + lr;
                b[nf] = ld_frag_g(B2T + w * 128 + k0);
            }
            #pragma unroll
            for (int mf = 0; mf < 4; ++mf)
                #pragma unroll
                for (int nf = 0; nf < 8; ++nf)
                    acc2[mf][nf] = __builtin_amdgcn_mfma_f32_16x16x32_bf16(
                                       a[mf], b[nf], acc2[mf][nf], 0, 0, 0);
        }
        #pragma unroll
        for (int mf = 0; mf < 4; ++mf)
            #pragma unroll
            for (int rg = 0; rg < 4; ++rg) {
                int h = wv * 64 + mf * 16 + g * 4 + rg;
                float* row = outp + h * 256 + nh * 128 + lr;
                #pragma unroll
                for (int nf = 0; nf < 8; ++nf)
                    row[nf * 16] = acc2[mf][nf][rg] * scale + bias;
            }
    }
}

extern "C" void kernel_launch(void* const* d_in, const int* in_sizes, int n_in,
                              void* d_out, int out_size, void* d_ws, size_t ws_size,
                              hipStream_t stream) {
    const float* x          = (const float*)d_in[0];
    const int*   q_real     = (const int*)  d_in[1];
    const int*   q_imag     = (const int*)  d_in[2];
    const int*   q_bias     = (const int*)  d_in[3];
    const float* scale_real = (const float*)d_in[4];
    const float* min_real   = (const float*)d_in[5];
    const float* scale_imag = (const float*)d_in[6];
    const float* min_imag   = (const float*)d_in[7];
    const float* b_scale    = (const float*)d_in[8];
    const float* b_min      = (const float*)d_in[9];
    float* out = (float*)d_out;

    float* ws = (float*)d_ws;
    // float-unit offsets:
    // A1tab bf16 [0,16384) ; B2T bf16 [16384,32768) ; B1fT bf16 [32768,49152)
    // A2f bf16 [49152,81920) ; X fp32 planes [81920, +8388608) ; Y float2 after.
    unsigned short* A1tab = (unsigned short*)(ws);
    unsigned short* B2T   = (unsigned short*)(ws + 16384);
    unsigned short* B1fT  = (unsigned short*)(ws + 32768);
    unsigned short* A2f   = (unsigned short*)(ws + 49152);
    float*          Xws   = (float*) (ws + 81920);
    float2*         Yws   = (float2*)(ws + 81920 + 8388608);

    build_tables2<<<128, 256, 0, stream>>>(A1tab, B2T);
    build_fwd_tables<<<384, 256, 0, stream>>>(B1fT, A2f);
    fwd_mfma<<<NB * NCIN, 256, 0, stream>>>(x, B1fT, A2f, Xws);
    mix_kernel<<<dim3(64, 8), 256, 0, stream>>>(Xws, q_real, q_imag,
                                                scale_real, min_real,
                                                scale_imag, min_imag, Yws);
    inv_mfma<<<NB * NCOUT, 256, 0, stream>>>(Yws, A1tab, B2T,
                                             q_bias, b_scale, b_min, out);
}